// Round 2
// baseline (4721.846 us; speedup 1.0000x reference)
//
#include <hip/hip_runtime.h>

#define NUM_ENT  50000
#define NUM_REL  64
#define NUM_TRI  400000
#define NUM_EDGE (NUM_TRI + NUM_ENT)   // 450000
#define DIN      128
#define NUM_HEAD 8
#define DH       16

// order-preserving float<->uint for atomicMax-based segment max
__device__ __forceinline__ unsigned fenc(float f) {
    unsigned u = __float_as_uint(f);
    return (u & 0x80000000u) ? ~u : (u | 0x80000000u);
}
__device__ __forceinline__ float fdec(unsigned u) {
    unsigned b = (u & 0x80000000u) ? (u & 0x7FFFFFFFu) : ~u;
    return __uint_as_float(b);
}

// ---------------- kernel 1: tail in-degree ----------------
__global__ void k_freq(const int* __restrict__ trip, int* __restrict__ freq) {
    int i = blockIdx.x * blockDim.x + threadIdx.x;
    if (i < NUM_TRI) atomicAdd(&freq[trip[i * 3 + 2]], 1);
}

// ---------------- kernel 2: self_rel accumulation ----------------
__global__ void k_selfrel_acc(const int* __restrict__ trip, const float* __restrict__ emb_rel,
                              float* __restrict__ self_rel) {
    long long i = (long long)blockIdx.x * blockDim.x + threadIdx.x;
    if (i < (long long)NUM_TRI * DIN) {
        int e = (int)(i >> 7), d = (int)(i & 127);
        int tail = trip[e * 3 + 2];
        int rel  = trip[e * 3 + 1];
        atomicAdd(&self_rel[tail * DIN + d], emb_rel[rel * DIN + d]);
    }
}

// ---------------- kernel 3: self_rel normalize ----------------
__global__ void k_selfrel_norm(float* __restrict__ self_rel, const int* __restrict__ freq) {
    int i = blockIdx.x * blockDim.x + threadIdx.x;
    if (i < NUM_ENT * DIN) {
        int f = freq[i >> 7];
        self_rel[i] = (f > 0) ? self_rel[i] / (float)f : 0.0f;
    }
}

// ---------------- kernel 4: attention raw + segment max ----------------
__global__ void k_attn(const float* __restrict__ emb_ent, const float* __restrict__ emb_rel,
                       const int* __restrict__ trip, const float* __restrict__ self_rel,
                       const float* __restrict__ Wa, const float* __restrict__ ba,
                       const float* __restrict__ attn_vec,
                       float* __restrict__ attn_raw, unsigned* __restrict__ amax) {
    int e = blockIdx.x;
    int j = threadIdx.x;
    __shared__ float feat[3 * DIN];
    int tail, head;
    if (e < NUM_TRI) {
        head = trip[e * 3 + 0];
        int rel = trip[e * 3 + 1];
        tail = trip[e * 3 + 2];
        feat[2 * DIN + j] = emb_rel[rel * DIN + j];
    } else {
        int idx = e - NUM_TRI;
        tail = idx; head = idx;
        feat[2 * DIN + j] = self_rel[idx * DIN + j];
    }
    feat[j]        = emb_ent[tail * DIN + j];
    feat[DIN + j]  = emb_ent[head * DIN + j];
    __syncthreads();

    float acc = ba[j];
#pragma unroll 8
    for (int k = 0; k < 3 * DIN; k++)
        acc += feat[k] * Wa[k * DIN + j];

    float h = tanhf(acc);
    float p = h * attn_vec[j];
    // reduce within each group of 16 lanes (one head)
#pragma unroll
    for (int off = 8; off > 0; off >>= 1)
        p += __shfl_xor(p, off, 16);
    if ((j & 15) == 0) {
        int hd = j >> 4;
        attn_raw[e * NUM_HEAD + hd] = p;
        atomicMax(&amax[tail * NUM_HEAD + hd], fenc(p));
    }
}

// ---------------- kernel 5: exp + segment sum ----------------
__global__ void k_expsum(const int* __restrict__ trip, const unsigned* __restrict__ amax,
                         float* __restrict__ attn, float* __restrict__ asum) {
    int i = blockIdx.x * blockDim.x + threadIdx.x;
    if (i < NUM_EDGE * NUM_HEAD) {
        int e = i >> 3, hd = i & 7;
        int tail = (e < NUM_TRI) ? trip[e * 3 + 2] : (e - NUM_TRI);
        float v = expf(attn[i] - fdec(amax[tail * NUM_HEAD + hd]));
        attn[i] = v;
        atomicAdd(&asum[tail * NUM_HEAD + hd], v);
    }
}

// ---------------- kernel 6: message GEMV + weighted scatter ----------------
__global__ void k_msg(const float* __restrict__ emb_ent, const float* __restrict__ emb_rel,
                      const int* __restrict__ trip, const float* __restrict__ self_rel,
                      const float* __restrict__ Wg, const float* __restrict__ bg,
                      const float* __restrict__ attn_val, const float* __restrict__ asum,
                      float* __restrict__ out) {
    int e = blockIdx.x;
    int j = threadIdx.x;
    __shared__ float feat[2 * DIN];
    int tail, head;
    if (e < NUM_TRI) {
        head = trip[e * 3 + 0];
        int rel = trip[e * 3 + 1];
        tail = trip[e * 3 + 2];
        feat[DIN + j] = emb_rel[rel * DIN + j];
    } else {
        int idx = e - NUM_TRI;
        tail = idx; head = idx;
        feat[DIN + j] = self_rel[idx * DIN + j];
    }
    feat[j] = emb_ent[head * DIN + j];
    __syncthreads();

    float acc = bg[j];
#pragma unroll 8
    for (int k = 0; k < 2 * DIN; k++)
        acc += feat[k] * Wg[k * DIN + j];

    int hd = j >> 4;
    float beta = attn_val[e * NUM_HEAD + hd] / (asum[tail * NUM_HEAD + hd] + 1e-16f);
    atomicAdd(&out[tail * DIN + j], beta * acc);
}

extern "C" void kernel_launch(void* const* d_in, const int* in_sizes, int n_in,
                              void* d_out, int out_size, void* d_ws, size_t ws_size,
                              hipStream_t stream) {
    const float* emb_ent  = (const float*)d_in[0];
    const float* emb_rel  = (const float*)d_in[1];
    const int*   trip     = (const int*)d_in[2];
    const float* Wa       = (const float*)d_in[3];
    const float* ba       = (const float*)d_in[4];
    const float* attn_vec = (const float*)d_in[5];
    const float* Wg       = (const float*)d_in[6];
    const float* bg       = (const float*)d_in[7];
    float* out = (float*)d_out;

    // workspace layout (element offsets on a float* base)
    float* wsf = (float*)d_ws;
    float*    self_rel = wsf;                              // 6,400,000 f
    float*    attn     = wsf + 6400000;                    // 3,600,000 f
    float*    asum     = wsf + 10000000;                   //   400,000 f
    unsigned* amax     = (unsigned*)(wsf + 10400000);      //   400,000 u
    int*      freq     = (int*)(wsf + 10800000);           //    50,000 i
    const size_t used_bytes = (size_t)10850000 * 4;        // ~43.4 MB

    hipMemsetAsync(d_ws, 0, used_bytes, stream);
    hipMemsetAsync(d_out, 0, (size_t)out_size * sizeof(float), stream);

    k_freq<<<(NUM_TRI + 255) / 256, 256, 0, stream>>>(trip, freq);

    {
        long long tot = (long long)NUM_TRI * DIN;
        int blocks = (int)((tot + 255) / 256);
        k_selfrel_acc<<<blocks, 256, 0, stream>>>(trip, emb_rel, self_rel);
    }

    k_selfrel_norm<<<(NUM_ENT * DIN + 255) / 256, 256, 0, stream>>>(self_rel, freq);

    k_attn<<<NUM_EDGE, DIN, 0, stream>>>(emb_ent, emb_rel, trip, self_rel,
                                         Wa, ba, attn_vec, attn, amax);

    k_expsum<<<(NUM_EDGE * NUM_HEAD + 255) / 256, 256, 0, stream>>>(trip, amax, attn, asum);

    k_msg<<<NUM_EDGE, DIN, 0, stream>>>(emb_ent, emb_rel, trip, self_rel,
                                        Wg, bg, attn, asum, out);
}

// Round 3
// 786.989 us; speedup vs baseline: 5.9999x; 5.9999x over previous
//
#include <hip/hip_runtime.h>

#define NUM_ENT  50000
#define NUM_REL  64
#define NUM_TRI  400000
#define NUM_EDGE (NUM_TRI + NUM_ENT)   // 450000
#define DIN      128
#define NUM_HEAD 8
#define DH       16

// order-preserving float<->uint for atomicMax-based segment max
__device__ __forceinline__ unsigned fenc(float f) {
    unsigned u = __float_as_uint(f);
    return (u & 0x80000000u) ? ~u : (u | 0x80000000u);
}
__device__ __forceinline__ float fdec(unsigned u) {
    unsigned b = (u & 0x80000000u) ? (u & 0x7FFFFFFFu) : ~u;
    return __uint_as_float(b);
}

// ---------------- hist + freq (float counts, exact up to 2^24) ----------------
__global__ void k_histfreq(const int* __restrict__ trip, float* __restrict__ histf,
                           float* __restrict__ freqf) {
    int i = blockIdx.x * blockDim.x + threadIdx.x;
    if (i < NUM_TRI) {
        int r = trip[i * 3 + 1];
        int t = trip[i * 3 + 2];
        atomicAdd(&histf[t * NUM_REL + r], 1.0f);
        atomicAdd(&freqf[t], 1.0f);
    }
}

// ---------------- tiny rel-table GEMMs: T = emb_rel @ Wblk (64x128) ----------------
__global__ void k_small(const float* __restrict__ emb_rel, const float* __restrict__ Wa,
                        const float* __restrict__ Wg, float* __restrict__ Ta,
                        float* __restrict__ Tg) {
    int row = blockIdx.x >> 1;
    int tbl = blockIdx.x & 1;
    int j = threadIdx.x;
    const float* W = tbl ? (Wg + 128 * DIN) : (Wa + 256 * DIN);
    float* outp    = tbl ? Tg : Ta;
    __shared__ float s[DIN];
    s[j] = emb_rel[row * DIN + j];
    __syncthreads();
    float acc = 0.0f;
#pragma unroll 8
    for (int k = 0; k < DIN; k++) acc += s[k] * W[k * DIN + j];
    outp[row * DIN + j] = acc;
}

// ---------------- entity GEMM: out = X(50000x128) @ W(128x128) + bias ----------------
// block 256 thr; M_BLK=64; per-thread 8 rows x 4 cols
__global__ __launch_bounds__(256) void k_ent(const float* __restrict__ X,
                                             const float* __restrict__ W,
                                             const float* __restrict__ bias,
                                             float* __restrict__ outp) {
    __shared__ float As[64][132];
    int tid = threadIdx.x;
    int m0 = blockIdx.x * 64;

    // stage A tile: 64 rows x 128 cols = 2048 float4
    for (int i = 0; i < 8; i++) {
        int v = tid + i * 256;           // float4 index
        int row = v >> 5;                // 32 float4 per row
        int c4 = v & 31;
        int gr = m0 + row;
        if (gr >= NUM_ENT) gr = NUM_ENT - 1;
        float4 x = *(const float4*)&X[gr * DIN + c4 * 4];
        *(float4*)&As[row][c4 * 4] = x;
    }
    __syncthreads();

    int tx = tid & 31;        // col group: cols tx*4..tx*4+3
    int ty = tid >> 5;        // row group: rows ty*8..ty*8+7
    float4 acc[8];
#pragma unroll
    for (int e = 0; e < 8; e++) acc[e] = make_float4(0.f, 0.f, 0.f, 0.f);

#pragma unroll 4
    for (int k4 = 0; k4 < 32; k4++) {
        float4 b[4];
#pragma unroll
        for (int q = 0; q < 4; q++)
            b[q] = *(const float4*)&W[(k4 * 4 + q) * DIN + tx * 4];
        float4 a[8];
#pragma unroll
        for (int e = 0; e < 8; e++)
            a[e] = *(const float4*)&As[ty * 8 + e][k4 * 4];
#pragma unroll
        for (int e = 0; e < 8; e++) {
            acc[e].x += a[e].x * b[0].x; acc[e].y += a[e].x * b[0].y;
            acc[e].z += a[e].x * b[0].z; acc[e].w += a[e].x * b[0].w;
            acc[e].x += a[e].y * b[1].x; acc[e].y += a[e].y * b[1].y;
            acc[e].z += a[e].y * b[1].z; acc[e].w += a[e].y * b[1].w;
            acc[e].x += a[e].z * b[2].x; acc[e].y += a[e].z * b[2].y;
            acc[e].z += a[e].z * b[2].z; acc[e].w += a[e].z * b[2].w;
            acc[e].x += a[e].w * b[3].x; acc[e].y += a[e].w * b[3].y;
            acc[e].z += a[e].w * b[3].z; acc[e].w += a[e].w * b[3].w;
        }
    }

    float4 bv = make_float4(0.f, 0.f, 0.f, 0.f);
    if (bias) bv = *(const float4*)&bias[tx * 4];
#pragma unroll
    for (int e = 0; e < 8; e++) {
        int gr = m0 + ty * 8 + e;
        if (gr < NUM_ENT) {
            float4 r = acc[e];
            r.x += bv.x; r.y += bv.y; r.z += bv.z; r.w += bv.w;
            *(float4*)&outp[gr * DIN + tx * 4] = r;
        }
    }
}

// ---------------- attention edge kernel ----------------
__global__ void k_attn_e(const int* __restrict__ trip, const float* __restrict__ Pt,
                         const float* __restrict__ Ph, const float* __restrict__ Ta,
                         const float* __restrict__ histf, const float* __restrict__ freqf,
                         const float* __restrict__ attn_vec,
                         float* __restrict__ attn, unsigned* __restrict__ amax) {
    int tid = threadIdx.x;
    int e = blockIdx.x * 2 + (tid >> 7);
    int j = tid & 127;
    int t, h;
    float relp;
    if (e < NUM_TRI) {
        h = trip[e * 3 + 0];
        int r = trip[e * 3 + 1];
        t = trip[e * 3 + 2];
        relp = Ta[r * DIN + j];
    } else {
        int i = e - NUM_TRI;
        t = i; h = i;
        float f = freqf[i];
        float acc = 0.0f;
#pragma unroll 8
        for (int q = 0; q < NUM_REL; q++) acc += histf[i * NUM_REL + q] * Ta[q * DIN + j];
        relp = (f > 0.0f) ? acc / f : 0.0f;
    }
    float v = Pt[t * DIN + j] + Ph[h * DIN + j] + relp;
    float p = tanhf(v) * attn_vec[j];
#pragma unroll
    for (int off = 8; off > 0; off >>= 1) p += __shfl_xor(p, off, 16);
    if ((j & 15) == 0) {
        int hd = j >> 4;
        attn[e * NUM_HEAD + hd] = p;
        atomicMax(&amax[t * NUM_HEAD + hd], fenc(p));
    }
}

// ---------------- exp + segment sum ----------------
__global__ void k_expsum(const int* __restrict__ trip, const unsigned* __restrict__ amax,
                         float* __restrict__ attn, float* __restrict__ asum) {
    int i = blockIdx.x * blockDim.x + threadIdx.x;
    if (i < NUM_EDGE * NUM_HEAD) {
        int e = i >> 3, hd = i & 7;
        int tail = (e < NUM_TRI) ? trip[e * 3 + 2] : (e - NUM_TRI);
        float v = expf(attn[i] - fdec(amax[tail * NUM_HEAD + hd]));
        attn[i] = v;
        atomicAdd(&asum[tail * NUM_HEAD + hd], v);
    }
}

// ---------------- message edge kernel ----------------
__global__ void k_msg_e(const int* __restrict__ trip, const float* __restrict__ Gh,
                        const float* __restrict__ Tg, const float* __restrict__ histf,
                        const float* __restrict__ freqf, const float* __restrict__ attn,
                        const float* __restrict__ asum, float* __restrict__ outp) {
    int tid = threadIdx.x;
    int e = blockIdx.x * 2 + (tid >> 7);
    int j = tid & 127;
    int t, h;
    float relp;
    if (e < NUM_TRI) {
        h = trip[e * 3 + 0];
        int r = trip[e * 3 + 1];
        t = trip[e * 3 + 2];
        relp = Tg[r * DIN + j];
    } else {
        int i = e - NUM_TRI;
        t = i; h = i;
        float f = freqf[i];
        float acc = 0.0f;
#pragma unroll 8
        for (int q = 0; q < NUM_REL; q++) acc += histf[i * NUM_REL + q] * Tg[q * DIN + j];
        relp = (f > 0.0f) ? acc / f : 0.0f;
    }
    float msg = Gh[h * DIN + j] + relp;
    int hd = j >> 4;
    float beta = attn[e * NUM_HEAD + hd] / (asum[t * NUM_HEAD + hd] + 1e-16f);
    atomicAdd(&outp[t * DIN + j], beta * msg);
}

extern "C" void kernel_launch(void* const* d_in, const int* in_sizes, int n_in,
                              void* d_out, int out_size, void* d_ws, size_t ws_size,
                              hipStream_t stream) {
    const float* emb_ent  = (const float*)d_in[0];
    const float* emb_rel  = (const float*)d_in[1];
    const int*   trip     = (const int*)d_in[2];
    const float* Wa       = (const float*)d_in[3];
    const float* ba       = (const float*)d_in[4];
    const float* attn_vec = (const float*)d_in[5];
    const float* Wg       = (const float*)d_in[6];
    const float* bg       = (const float*)d_in[7];
    float* out = (float*)d_out;

    // workspace layout (float elements)
    float* wsf = (float*)d_ws;
    float*    A     = wsf;                         // P_t, later G_h   6,400,000
    float*    B     = wsf + 6400000;               // P_h              6,400,000
    float*    Ta    = wsf + 12800000;              //     8,192
    float*    Tg    = wsf + 12808192;              //     8,192
    float*    attn  = wsf + 12816384;              // 3,600,000
    float*    histf = wsf + 16416384;              // 3,200,000
    float*    freqf = wsf + 19616384;              //    50,000
    float*    asum  = wsf + 19666384;              //   400,000
    unsigned* amax  = (unsigned*)(wsf + 20066384); //   400,000
    // total 20,466,384 floats ≈ 81.9 MB

    // zero only what must start at 0: histf..amax (contiguous) + out
    hipMemsetAsync(histf, 0, (size_t)(3200000 + 50000 + 400000 + 400000) * 4, stream);
    hipMemsetAsync(d_out, 0, (size_t)out_size * sizeof(float), stream);

    k_histfreq<<<(NUM_TRI + 255) / 256, 256, 0, stream>>>(trip, histf, freqf);

    k_small<<<NUM_REL * 2, DIN, 0, stream>>>(emb_rel, Wa, Wg, Ta, Tg);

    const int egrid = (NUM_ENT + 63) / 64;   // 782
    k_ent<<<egrid, 256, 0, stream>>>(emb_ent, Wa, ba, A);                 // P_t = ent@Wa_t + ba
    k_ent<<<egrid, 256, 0, stream>>>(emb_ent, Wa + 128 * DIN, nullptr, B); // P_h = ent@Wa_h

    k_attn_e<<<NUM_EDGE / 2, 256, 0, stream>>>(trip, A, B, Ta, histf, freqf,
                                               attn_vec, attn, amax);

    k_expsum<<<(NUM_EDGE * NUM_HEAD + 255) / 256, 256, 0, stream>>>(trip, amax, attn, asum);

    k_ent<<<egrid, 256, 0, stream>>>(emb_ent, Wg, bg, A);                 // G_h = ent@Wg_h + bg (reuse A)

    k_msg_e<<<NUM_EDGE / 2, 256, 0, stream>>>(trip, A, Tg, histf, freqf,
                                              attn, asum, out);
}

// Round 4
// 348.038 us; speedup vs baseline: 13.5671x; 2.2612x over previous
//
#include <hip/hip_runtime.h>
#include <math.h>

#define NUM_ENT  50000
#define NUM_REL  64
#define NUM_TRI  400000
#define DIN      128
#define NUM_HEAD 8

#define SCAN_BLK 1024
#define NB       ((NUM_ENT + SCAN_BLK - 1) / SCAN_BLK)   // 49

// ---------------- kernel 1: tail in-degree ----------------
__global__ void k_freq(const int* __restrict__ trip, int* __restrict__ freq) {
    int i = blockIdx.x * blockDim.x + threadIdx.x;
    if (i < NUM_TRI) atomicAdd(&freq[trip[i * 3 + 2]], 1);
}

// ---------------- scan 1: per-chunk inclusive scan + chunk totals ----------------
__global__ __launch_bounds__(SCAN_BLK) void k_scan1(const int* __restrict__ freq,
                                                    int* __restrict__ incl,
                                                    int* __restrict__ btot) {
    int gid = blockIdx.x * SCAN_BLK + threadIdx.x;
    int lane = threadIdx.x & 63;
    int wv = threadIdx.x >> 6;
    int s = (gid < NUM_ENT) ? freq[gid] : 0;
#pragma unroll
    for (int off = 1; off < 64; off <<= 1) {
        int n = __shfl_up(s, off, 64);
        if (lane >= off) s += n;
    }
    __shared__ int wtot[16];
    if (lane == 63) wtot[wv] = s;
    __syncthreads();
    if (wv == 0 && lane < 16) {
        int w = wtot[lane];
#pragma unroll
        for (int off = 1; off < 16; off <<= 1) {
            int n = __shfl_up(w, off, 64);
            if (lane >= off) w += n;
        }
        wtot[lane] = w;
    }
    __syncthreads();
    if (wv > 0) s += wtot[wv - 1];
    if (gid < NUM_ENT) incl[gid] = s;
    if (threadIdx.x == SCAN_BLK - 1) btot[blockIdx.x] = s;
}

// ---------------- scan 2: inclusive scan of the 49 chunk totals ----------------
__global__ void k_scan2(int* __restrict__ btot) {
    int lane = threadIdx.x;
    int v = (lane < NB) ? btot[lane] : 0;
#pragma unroll
    for (int off = 1; off < 64; off <<= 1) {
        int n = __shfl_up(v, off, 64);
        if (lane >= off) v += n;
    }
    if (lane < NB) btot[lane] = v;
}

// ---------------- scan 3: exclusive offsets = incl + chunkbase - freq ----------------
__global__ __launch_bounds__(SCAN_BLK) void k_scan3(int* __restrict__ incl_to_excl,
                                                    const int* __restrict__ freq,
                                                    const int* __restrict__ btot) {
    int gid = blockIdx.x * SCAN_BLK + threadIdx.x;
    if (gid < NUM_ENT) {
        int base = (blockIdx.x > 0) ? btot[blockIdx.x - 1] : 0;
        incl_to_excl[gid] = incl_to_excl[gid] + base - freq[gid];
    }
}

// ---------------- scatter: tail-sorted edge list ----------------
__global__ void k_scatter(const int* __restrict__ trip, const int* __restrict__ excl,
                          int* __restrict__ cursor, int* __restrict__ elist) {
    int i = blockIdx.x * blockDim.x + threadIdx.x;
    if (i < NUM_TRI) {
        int t = trip[i * 3 + 2];
        int pos = excl[t] + atomicAdd(&cursor[t], 1);
        elist[pos] = i;
    }
}

// ---------------- tiny rel-table GEMMs: Ta = emb_rel@Wa_r, Tg = emb_rel@Wg_r ----------------
__global__ void k_small(const float* __restrict__ emb_rel, const float* __restrict__ Wa,
                        const float* __restrict__ Wg, float* __restrict__ Ta,
                        float* __restrict__ Tg) {
    int row = blockIdx.x >> 1;
    int tbl = blockIdx.x & 1;
    int j = threadIdx.x;
    const float* W = tbl ? (Wg + 128 * DIN) : (Wa + 256 * DIN);
    float* outp    = tbl ? Tg : Ta;
    __shared__ float s[DIN];
    s[j] = emb_rel[row * DIN + j];
    __syncthreads();
    float acc = 0.0f;
#pragma unroll 8
    for (int k = 0; k < DIN; k++) acc += s[k] * W[k * DIN + j];
    outp[row * DIN + j] = acc;
}

// ---------------- entity GEMMs (x3 fused): Pt = E@Wa_t + ba, Ph = E@Wa_h, Gh = E@Wg_h + bg
__global__ __launch_bounds__(256) void k_ent3(const float* __restrict__ X,
                                              const float* __restrict__ Wa,
                                              const float* __restrict__ ba,
                                              const float* __restrict__ Wg,
                                              const float* __restrict__ bg,
                                              float* __restrict__ Pt,
                                              float* __restrict__ Ph,
                                              float* __restrict__ Gh) {
    __shared__ float As[64][132];
    int tid = threadIdx.x;
    int m0 = blockIdx.x * 64;

    for (int i = 0; i < 8; i++) {
        int v = tid + i * 256;
        int row = v >> 5;
        int c4 = v & 31;
        int gr = m0 + row;
        if (gr >= NUM_ENT) gr = NUM_ENT - 1;
        *(float4*)&As[row][c4 * 4] = *(const float4*)&X[gr * DIN + c4 * 4];
    }
    __syncthreads();

    int tx = tid & 31;
    int ty = tid >> 5;

    const float* Ws[3];  Ws[0] = Wa;  Ws[1] = Wa + 128 * DIN;  Ws[2] = Wg;
    const float* bs[3];  bs[0] = ba;  bs[1] = nullptr;         bs[2] = bg;
    float*       os[3];  os[0] = Pt;  os[1] = Ph;              os[2] = Gh;

    for (int s = 0; s < 3; s++) {
        const float* W = Ws[s];
        float4 acc[8];
#pragma unroll
        for (int e = 0; e < 8; e++) acc[e] = make_float4(0.f, 0.f, 0.f, 0.f);
#pragma unroll 4
        for (int k4 = 0; k4 < 32; k4++) {
            float4 b[4];
#pragma unroll
            for (int q = 0; q < 4; q++)
                b[q] = *(const float4*)&W[(k4 * 4 + q) * DIN + tx * 4];
            float4 a[8];
#pragma unroll
            for (int e = 0; e < 8; e++)
                a[e] = *(const float4*)&As[ty * 8 + e][k4 * 4];
#pragma unroll
            for (int e = 0; e < 8; e++) {
                acc[e].x += a[e].x * b[0].x; acc[e].y += a[e].x * b[0].y;
                acc[e].z += a[e].x * b[0].z; acc[e].w += a[e].x * b[0].w;
                acc[e].x += a[e].y * b[1].x; acc[e].y += a[e].y * b[1].y;
                acc[e].z += a[e].y * b[1].z; acc[e].w += a[e].y * b[1].w;
                acc[e].x += a[e].z * b[2].x; acc[e].y += a[e].z * b[2].y;
                acc[e].z += a[e].z * b[2].z; acc[e].w += a[e].z * b[2].w;
                acc[e].x += a[e].w * b[3].x; acc[e].y += a[e].w * b[3].y;
                acc[e].z += a[e].w * b[3].z; acc[e].w += a[e].w * b[3].w;
            }
        }
        float4 bv = make_float4(0.f, 0.f, 0.f, 0.f);
        if (bs[s]) bv = *(const float4*)&bs[s][tx * 4];
#pragma unroll
        for (int e = 0; e < 8; e++) {
            int gr = m0 + ty * 8 + e;
            if (gr < NUM_ENT) {
                float4 r = acc[e];
                r.x += bv.x; r.y += bv.y; r.z += bv.z; r.w += bv.w;
                *(float4*)&os[s][gr * DIN + tx * 4] = r;
            }
        }
        __syncthreads();   // keep As live/consistent across s (no rewrite, just ordering)
    }
}

// ---------------- fused per-tail flash pass: attn + softmax + weighted msg ----------------
__global__ __launch_bounds__(128) void k_fused(const int* __restrict__ trip,
                                               const int* __restrict__ elist,
                                               const int* __restrict__ excl,
                                               const int* __restrict__ freq,
                                               const float* __restrict__ Pt,
                                               const float* __restrict__ Ph,
                                               const float* __restrict__ Gh,
                                               const float* __restrict__ Ta,
                                               const float* __restrict__ Tg,
                                               const float* __restrict__ attn_vec,
                                               float* __restrict__ out) {
    int t = blockIdx.x;
    int j = threadIdx.x;
    int off = excl[t];
    int deg = freq[t];

    float ptj = Pt[t * DIN + j];
    float av  = attn_vec[j];

    float m = -INFINITY, l = 0.f, acc = 0.f;
    float sumTa = 0.f, sumTg = 0.f;

    for (int it = 0; it <= deg; it++) {
        float paj, gmj;
        if (it < deg) {
            int e = elist[off + it];
            int h = trip[e * 3 + 0];
            int r = trip[e * 3 + 1];
            float taj = Ta[r * DIN + j];
            float tgj = Tg[r * DIN + j];
            sumTa += taj;
            sumTg += tgj;
            paj = Ph[h * DIN + j] + taj;
            gmj = Gh[h * DIN + j] + tgj;
        } else {
            // self edge: rel part = mean of real edges' Ta/Tg rows (0 if deg==0)
            float inv = (deg > 0) ? 1.f / (float)deg : 0.f;
            paj = Ph[t * DIN + j] + sumTa * inv;
            gmj = Gh[t * DIN + j] + sumTg * inv;
        }
        float x = ptj + paj;
        x = fminf(fmaxf(x, -15.f), 15.f);
        float ex = __expf(2.f * x);
        float p = ((ex - 1.f) / (ex + 1.f)) * av;   // tanh(x)*attn_vec
#pragma unroll
        for (int o = 8; o; o >>= 1) p += __shfl_xor(p, o, 16);
        float nm = fmaxf(m, p);
        float al = __expf(m - nm);
        float w  = __expf(p - nm);
        l   = l * al + w;
        acc = acc * al + w * gmj;
        m = nm;
    }
    out[t * DIN + j] = acc / (l + 1e-16f);
}

extern "C" void kernel_launch(void* const* d_in, const int* in_sizes, int n_in,
                              void* d_out, int out_size, void* d_ws, size_t ws_size,
                              hipStream_t stream) {
    const float* emb_ent  = (const float*)d_in[0];
    const float* emb_rel  = (const float*)d_in[1];
    const int*   trip     = (const int*)d_in[2];
    const float* Wa       = (const float*)d_in[3];
    const float* ba       = (const float*)d_in[4];
    const float* attn_vec = (const float*)d_in[5];
    const float* Wg       = (const float*)d_in[6];
    const float* bg       = (const float*)d_in[7];
    float* out = (float*)d_out;

    // workspace layout (float/int elements)
    float* wsf = (float*)d_ws;
    float* Pt   = wsf;                         //  6,400,000
    float* Ph   = wsf + 6400000;               //  6,400,000
    float* Gh   = wsf + 12800000;              //  6,400,000
    float* Ta   = wsf + 19200000;              //      8,192
    float* Tg   = wsf + 19208192;              //      8,192
    int*   freq   = (int*)(wsf + 19216384);    //     50,000  (zeroed)
    int*   cursor = freq + 50000;              //     50,000  (zeroed)
    int*   btot   = cursor + 50000;            //         64  (zeroed)
    int*   excl   = btot + 64;                 //     50,000
    int*   elist  = excl + 50000;              //    400,000
    // total ≈ 19,766,448 * 4 B ≈ 79.1 MB

    hipMemsetAsync(freq, 0, (size_t)(50000 + 50000 + 64) * 4, stream);

    k_freq<<<(NUM_TRI + 255) / 256, 256, 0, stream>>>(trip, freq);

    k_scan1<<<NB, SCAN_BLK, 0, stream>>>(freq, excl, btot);   // excl holds inclusive scan
    k_scan2<<<1, 64, 0, stream>>>(btot);
    k_scan3<<<NB, SCAN_BLK, 0, stream>>>(excl, freq, btot);   // now exclusive offsets

    k_scatter<<<(NUM_TRI + 255) / 256, 256, 0, stream>>>(trip, excl, cursor, elist);

    k_small<<<NUM_REL * 2, DIN, 0, stream>>>(emb_rel, Wa, Wg, Ta, Tg);

    k_ent3<<<(NUM_ENT + 63) / 64, 256, 0, stream>>>(emb_ent, Wa, ba, Wg, bg, Pt, Ph, Gh);

    k_fused<<<NUM_ENT, 128, 0, stream>>>(trip, elist, excl, freq,
                                         Pt, Ph, Gh, Ta, Tg, attn_vec, out);
}

// Round 5
// 318.125 us; speedup vs baseline: 14.8428x; 1.0940x over previous
//
#include <hip/hip_runtime.h>
#include <math.h>

#define NUM_ENT  50000
#define NUM_REL  64
#define NUM_TRI  400000
#define DIN      128

#define ENT3_BLOCKS  782                 // ceil(50000/64)
#define SMALL_BLOCKS 64                  // one rel row per block (both tables)
#define FREQ_BLOCKS  1563                // ceil(400000/256)
#define PRE_BLOCKS   (ENT3_BLOCKS + SMALL_BLOCKS + FREQ_BLOCKS)

#define SCAN_BLK 1024
#define NCHUNK   ((NUM_ENT + SCAN_BLK - 1) / SCAN_BLK)   // 49

// ---------- float4 helpers ----------
__device__ __forceinline__ float4 f4add(float4 a, float4 b) {
    return make_float4(a.x + b.x, a.y + b.y, a.z + b.z, a.w + b.w);
}

__device__ __forceinline__ void tile_fma(float4 acc[8], const float4 a[8],
                                         float4 b0, float4 b1, float4 b2, float4 b3) {
#pragma unroll
    for (int e = 0; e < 8; e++) {
        float4 r = acc[e]; float4 ae = a[e];
        r.x += ae.x * b0.x; r.y += ae.x * b0.y; r.z += ae.x * b0.z; r.w += ae.x * b0.w;
        r.x += ae.y * b1.x; r.y += ae.y * b1.y; r.z += ae.y * b1.z; r.w += ae.y * b1.w;
        r.x += ae.z * b2.x; r.y += ae.z * b2.y; r.z += ae.z * b2.z; r.w += ae.z * b2.w;
        r.x += ae.w * b3.x; r.y += ae.w * b3.y; r.z += ae.w * b3.z; r.w += ae.w * b3.w;
        acc[e] = r;
    }
}

// tanh(x)*av summed over 4 components; tanh via fast exp + fast rcp
__device__ __forceinline__ float tanh_dot4(float4 x, float4 av) {
    float r = 0.f;
    {
        float c = fminf(fmaxf(x.x, -15.f), 15.f); float e = __expf(2.f * c);
        r += (1.f - 2.f * __builtin_amdgcn_rcpf(e + 1.f)) * av.x;
    }
    {
        float c = fminf(fmaxf(x.y, -15.f), 15.f); float e = __expf(2.f * c);
        r += (1.f - 2.f * __builtin_amdgcn_rcpf(e + 1.f)) * av.y;
    }
    {
        float c = fminf(fmaxf(x.z, -15.f), 15.f); float e = __expf(2.f * c);
        r += (1.f - 2.f * __builtin_amdgcn_rcpf(e + 1.f)) * av.z;
    }
    {
        float c = fminf(fmaxf(x.w, -15.f), 15.f); float e = __expf(2.f * c);
        r += (1.f - 2.f * __builtin_amdgcn_rcpf(e + 1.f)) * av.w;
    }
    return r;
}

// ---------------- K1: grid-partitioned [ent GEMM x3 | rel tables | freq hist] ----------------
__global__ __launch_bounds__(256) void k_pre(const float* __restrict__ X,
                                             const float* __restrict__ emb_rel,
                                             const int* __restrict__ trip,
                                             const float* __restrict__ Wa,
                                             const float* __restrict__ ba,
                                             const float* __restrict__ Wg,
                                             const float* __restrict__ bg,
                                             float* __restrict__ Pt,
                                             float* __restrict__ Ph,
                                             float* __restrict__ Gh,
                                             float* __restrict__ Ta,
                                             float* __restrict__ Tg,
                                             int* __restrict__ freq) {
    __shared__ float As[64][132];
    int b = blockIdx.x;
    int tid = threadIdx.x;

    if (b < ENT3_BLOCKS) {
        // out = X(50000x128) @ {Wa_t, Wa_h, Wg_h} ; 64 rows/block, 8x4 per thread
        int m0 = b * 64;
        for (int i = 0; i < 8; i++) {
            int v = tid + i * 256;
            int row = v >> 5;
            int c4 = v & 31;
            int gr = m0 + row;
            if (gr >= NUM_ENT) gr = NUM_ENT - 1;
            *(float4*)&As[row][c4 * 4] = *(const float4*)&X[gr * DIN + c4 * 4];
        }
        __syncthreads();

        int tx = tid & 31;
        int ty = tid >> 5;
        const float* W0 = Wa;              // tail rows of Wa
        const float* W1 = Wa + 128 * DIN;  // head rows of Wa
        const float* W2 = Wg;              // head rows of Wg

        float4 acc0[8], acc1[8], acc2[8];
#pragma unroll
        for (int e = 0; e < 8; e++) {
            acc0[e] = make_float4(0.f, 0.f, 0.f, 0.f);
            acc1[e] = make_float4(0.f, 0.f, 0.f, 0.f);
            acc2[e] = make_float4(0.f, 0.f, 0.f, 0.f);
        }

#pragma unroll 2
        for (int k4 = 0; k4 < 32; k4++) {
            float4 a[8];
#pragma unroll
            for (int e = 0; e < 8; e++)
                a[e] = *(const float4*)&As[ty * 8 + e][k4 * 4];
            {
                float4 b0 = *(const float4*)&W0[(k4 * 4 + 0) * DIN + tx * 4];
                float4 b1 = *(const float4*)&W0[(k4 * 4 + 1) * DIN + tx * 4];
                float4 b2 = *(const float4*)&W0[(k4 * 4 + 2) * DIN + tx * 4];
                float4 b3 = *(const float4*)&W0[(k4 * 4 + 3) * DIN + tx * 4];
                tile_fma(acc0, a, b0, b1, b2, b3);
            }
            {
                float4 b0 = *(const float4*)&W1[(k4 * 4 + 0) * DIN + tx * 4];
                float4 b1 = *(const float4*)&W1[(k4 * 4 + 1) * DIN + tx * 4];
                float4 b2 = *(const float4*)&W1[(k4 * 4 + 2) * DIN + tx * 4];
                float4 b3 = *(const float4*)&W1[(k4 * 4 + 3) * DIN + tx * 4];
                tile_fma(acc1, a, b0, b1, b2, b3);
            }
            {
                float4 b0 = *(const float4*)&W2[(k4 * 4 + 0) * DIN + tx * 4];
                float4 b1 = *(const float4*)&W2[(k4 * 4 + 1) * DIN + tx * 4];
                float4 b2 = *(const float4*)&W2[(k4 * 4 + 2) * DIN + tx * 4];
                float4 b3 = *(const float4*)&W2[(k4 * 4 + 3) * DIN + tx * 4];
                tile_fma(acc2, a, b0, b1, b2, b3);
            }
        }

        float4 bva = *(const float4*)&ba[tx * 4];
        float4 bvg = *(const float4*)&bg[tx * 4];
#pragma unroll
        for (int e = 0; e < 8; e++) {
            int gr = m0 + ty * 8 + e;
            if (gr < NUM_ENT) {
                *(float4*)&Pt[gr * DIN + tx * 4] = f4add(acc0[e], bva);
                *(float4*)&Ph[gr * DIN + tx * 4] = acc1[e];
                *(float4*)&Gh[gr * DIN + tx * 4] = f4add(acc2[e], bvg);
            }
        }
    } else if (b < ENT3_BLOCKS + SMALL_BLOCKS) {
        // Ta[row] = emb_rel[row] @ Wa_r ; Tg[row] = emb_rel[row] @ Wg_r
        int row = b - ENT3_BLOCKS;
        float* s = (float*)As;
        if (tid < DIN) s[tid] = emb_rel[row * DIN + tid];
        __syncthreads();
        int j = tid & 127;
        const float* W = (tid < 128) ? (Wa + 256 * DIN) : (Wg + 128 * DIN);
        float acc = 0.f;
#pragma unroll 8
        for (int k = 0; k < DIN; k++) acc += s[k] * W[k * DIN + j];
        float* o = (tid < 128) ? Ta : Tg;
        o[row * DIN + j] = acc;
    } else {
        int i = (b - ENT3_BLOCKS - SMALL_BLOCKS) * 256 + tid;
        if (i < NUM_TRI) atomicAdd(&freq[trip[i * 3 + 2]], 1);
    }
}

// ---------------- K2: single-block exclusive scan of freq -> excl ----------------
__global__ __launch_bounds__(SCAN_BLK) void k_scan(const int* __restrict__ freq,
                                                   int* __restrict__ excl) {
    __shared__ int wtot[16];
    __shared__ int sbase;
    if (threadIdx.x == 0) sbase = 0;
    __syncthreads();
    int lane = threadIdx.x & 63;
    int wv = threadIdx.x >> 6;
    for (int c = 0; c < NCHUNK; c++) {
        int gid = c * SCAN_BLK + threadIdx.x;
        int v = (gid < NUM_ENT) ? freq[gid] : 0;
        int s = v;
#pragma unroll
        for (int off = 1; off < 64; off <<= 1) {
            int n = __shfl_up(s, off, 64);
            if (lane >= off) s += n;
        }
        if (lane == 63) wtot[wv] = s;
        __syncthreads();
        if (threadIdx.x < 16) {
            int w = wtot[threadIdx.x];
#pragma unroll
            for (int off = 1; off < 16; off <<= 1) {
                int n = __shfl_up(w, off, 64);
                if ((int)threadIdx.x >= off) w += n;
            }
            wtot[threadIdx.x] = w;
        }
        __syncthreads();
        int s2 = s + ((wv > 0) ? wtot[wv - 1] : 0);
        int base = sbase;
        if (gid < NUM_ENT) excl[gid] = base + s2 - v;
        __syncthreads();
        if (threadIdx.x == 0) sbase = base + wtot[15];
        __syncthreads();
    }
}

// ---------------- K3: scatter tail-sorted (h,r) edge list ----------------
__global__ void k_scatter(const int* __restrict__ trip, const int* __restrict__ excl,
                          int* __restrict__ cursor, int2* __restrict__ elist2) {
    int i = blockIdx.x * blockDim.x + threadIdx.x;
    if (i < NUM_TRI) {
        int h = trip[i * 3 + 0];
        int r = trip[i * 3 + 1];
        int t = trip[i * 3 + 2];
        int pos = excl[t] + atomicAdd(&cursor[t], 1);
        elist2[pos] = make_int2(h, r);
    }
}

// ---------------- K4: fused per-tail online-softmax pass (float4, 32 lanes/tail) ----------------
__global__ __launch_bounds__(128) void k_fused(const int2* __restrict__ elist2,
                                               const int* __restrict__ excl,
                                               const int* __restrict__ freq,
                                               const float* __restrict__ Pt,
                                               const float* __restrict__ Ph,
                                               const float* __restrict__ Gh,
                                               const float* __restrict__ Ta,
                                               const float* __restrict__ Tg,
                                               const float* __restrict__ attn_vec,
                                               float* __restrict__ out) {
    int tid = threadIdx.x;
    int g = tid >> 5;                 // tail group within block
    int q = tid & 31;                 // lane within group
    int t = blockIdx.x * 4 + g;       // grid = 12500 -> t < 50000 always
    int off = excl[t];
    int deg = freq[t];
    int c = q * 4;                    // 4 consecutive cols, all within head (q>>2)

    float4 pt4 = *(const float4*)&Pt[t * DIN + c];
    float4 av4 = *(const float4*)&attn_vec[c];

    float m = -INFINITY, l = 0.f;
    float4 acc = make_float4(0.f, 0.f, 0.f, 0.f);
    float4 sTa = make_float4(0.f, 0.f, 0.f, 0.f);
    float4 sTg = make_float4(0.f, 0.f, 0.f, 0.f);

    for (int it = 0; it <= deg; it++) {
        float4 pa, gm;
        if (it < deg) {
            int2 hr = elist2[off + it];
            float4 ta = *(const float4*)&Ta[hr.y * DIN + c];
            float4 tg = *(const float4*)&Tg[hr.y * DIN + c];
            sTa = f4add(sTa, ta);
            sTg = f4add(sTg, tg);
            pa = f4add(*(const float4*)&Ph[hr.x * DIN + c], ta);
            gm = f4add(*(const float4*)&Gh[hr.x * DIN + c], tg);
        } else {
            float inv = (deg > 0) ? __builtin_amdgcn_rcpf((float)deg) : 0.f;
            pa = *(const float4*)&Ph[t * DIN + c];
            gm = *(const float4*)&Gh[t * DIN + c];
            pa.x += sTa.x * inv; pa.y += sTa.y * inv; pa.z += sTa.z * inv; pa.w += sTa.w * inv;
            gm.x += sTg.x * inv; gm.y += sTg.y * inv; gm.z += sTg.z * inv; gm.w += sTg.w * inv;
        }
        float p = tanh_dot4(f4add(pt4, pa), av4);
        p += __shfl_xor(p, 1);
        p += __shfl_xor(p, 2);        // 4-lane head reduce (16 dims = 4 lanes x 4)
        float nm = fmaxf(m, p);
        float al = __expf(m - nm);
        float w  = __expf(p - nm);
        l = l * al + w;
        acc.x = acc.x * al + w * gm.x;
        acc.y = acc.y * al + w * gm.y;
        acc.z = acc.z * al + w * gm.z;
        acc.w = acc.w * al + w * gm.w;
        m = nm;
    }
    float invl = 1.f / (l + 1e-16f);
    float4 r = make_float4(acc.x * invl, acc.y * invl, acc.z * invl, acc.w * invl);
    *(float4*)&out[t * DIN + c] = r;
}

extern "C" void kernel_launch(void* const* d_in, const int* in_sizes, int n_in,
                              void* d_out, int out_size, void* d_ws, size_t ws_size,
                              hipStream_t stream) {
    const float* emb_ent  = (const float*)d_in[0];
    const float* emb_rel  = (const float*)d_in[1];
    const int*   trip     = (const int*)d_in[2];
    const float* Wa       = (const float*)d_in[3];
    const float* ba       = (const float*)d_in[4];
    const float* attn_vec = (const float*)d_in[5];
    const float* Wg       = (const float*)d_in[6];
    const float* bg       = (const float*)d_in[7];
    float* out = (float*)d_out;

    // workspace layout (float elements)
    float* wsf = (float*)d_ws;
    float* Pt     = wsf;                          //  6,400,000
    float* Ph     = wsf + 6400000;                //  6,400,000
    float* Gh     = wsf + 12800000;               //  6,400,000
    float* Ta     = wsf + 19200000;               //      8,192
    float* Tg     = wsf + 19208192;               //      8,192
    int*   freq   = (int*)(wsf + 19216384);       //     50,000 (zeroed)
    int*   cursor = freq + 50000;                 //     50,000 (zeroed)
    int*   excl   = cursor + 50000;               //     50,000
    int2*  elist2 = (int2*)(excl + 50000);        //    400,000 int2 (8B-aligned)
    // total = 20,166,384 floats ~ 80.7 MB

    hipMemsetAsync(freq, 0, (size_t)100000 * 4, stream);

    k_pre<<<PRE_BLOCKS, 256, 0, stream>>>(emb_ent, emb_rel, trip, Wa, ba, Wg, bg,
                                          Pt, Ph, Gh, Ta, Tg, freq);

    k_scan<<<1, SCAN_BLK, 0, stream>>>(freq, excl);

    k_scatter<<<(NUM_TRI + 255) / 256, 256, 0, stream>>>(trip, excl, cursor, elist2);

    k_fused<<<NUM_ENT / 4, 128, 0, stream>>>(elist2, excl, freq,
                                             Pt, Ph, Gh, Ta, Tg, attn_vec, out);
}

// Round 6
// 274.196 us; speedup vs baseline: 17.2207x; 1.1602x over previous
//
#include <hip/hip_runtime.h>
#include <math.h>

#define NUM_ENT  50000
#define NUM_REL  64
#define NUM_TRI  400000
#define DIN      128

#define PACK_BLOCKS  24                  // 24*256*8 = 49152 = 3*128*128
#define SMALL_BLOCKS 64
#define FREQ_BLOCKS  1563                // ceil(400000/256)
#define PREP_BLOCKS  (PACK_BLOCKS + SMALL_BLOCKS + FREQ_BLOCKS)

#define SCAN_BLK 1024
#define NB       ((NUM_ENT + SCAN_BLK - 1) / SCAN_BLK)   // 49

typedef __attribute__((ext_vector_type(8))) short bf16x8;
typedef __attribute__((ext_vector_type(4))) float f32x4;

__device__ __forceinline__ float4 f4add(float4 a, float4 b) {
    return make_float4(a.x + b.x, a.y + b.y, a.z + b.z, a.w + b.w);
}

// fp32 -> bf16 bits, round-to-nearest-even
__device__ __forceinline__ unsigned short f2bf(float f) {
    unsigned u = __float_as_uint(f);
    unsigned r = ((u >> 16) & 1u) + 0x7fffu;
    return (unsigned short)((u + r) >> 16);
}

// tanh(x)*av summed over 4 components; tanh via fast exp + fast rcp
__device__ __forceinline__ float tanh_dot4(float4 x, float4 av) {
    float r = 0.f;
    {
        float c = fminf(fmaxf(x.x, -15.f), 15.f); float e = __expf(2.f * c);
        r += (1.f - 2.f * __builtin_amdgcn_rcpf(e + 1.f)) * av.x;
    }
    {
        float c = fminf(fmaxf(x.y, -15.f), 15.f); float e = __expf(2.f * c);
        r += (1.f - 2.f * __builtin_amdgcn_rcpf(e + 1.f)) * av.y;
    }
    {
        float c = fminf(fmaxf(x.z, -15.f), 15.f); float e = __expf(2.f * c);
        r += (1.f - 2.f * __builtin_amdgcn_rcpf(e + 1.f)) * av.z;
    }
    {
        float c = fminf(fmaxf(x.w, -15.f), 15.f); float e = __expf(2.f * c);
        r += (1.f - 2.f * __builtin_amdgcn_rcpf(e + 1.f)) * av.w;
    }
    return r;
}

// ---------------- K1: grid-partitioned [pack W->bf16 frags | rel tables | freq hist] ----
// Bpack flat index: (((s*8 + t)*4 + ks)*64 + lane)*8 + j
//   holds W_s[k = ks*32 + (lane>>4)*8 + j][n = t*16 + (lane&15)] as bf16.
__global__ __launch_bounds__(256) void k_prep(const float* __restrict__ emb_rel,
                                              const int* __restrict__ trip,
                                              const float* __restrict__ Wa,
                                              const float* __restrict__ Wg,
                                              unsigned short* __restrict__ Bpack,
                                              float* __restrict__ Ta,
                                              float* __restrict__ Tg,
                                              int* __restrict__ freq) {
    __shared__ float s[512];
    int b = blockIdx.x;
    int tid = threadIdx.x;

    if (b < PACK_BLOCKS) {
        for (int i = 0; i < 8; i++) {
            int idx = b * 2048 + i * 256 + tid;       // < 49152
            int j    = idx & 7;
            int lane = (idx >> 3) & 63;
            int ks   = (idx >> 9) & 3;
            int t    = (idx >> 11) & 7;
            int w    = idx >> 14;                     // weight select
            int k = ks * 32 + ((lane >> 4) << 3) + j;
            int n = t * 16 + (lane & 15);
            const float* W = (w == 0) ? Wa : (w == 1) ? (Wa + 128 * DIN) : Wg;
            Bpack[idx] = f2bf(W[k * DIN + n]);
        }
    } else if (b < PACK_BLOCKS + SMALL_BLOCKS) {
        // Ta[row] = emb_rel[row] @ Wa_r ; Tg[row] = emb_rel[row] @ Wg_r  (fp32)
        int row = b - PACK_BLOCKS;
        if (tid < DIN) s[tid] = emb_rel[row * DIN + tid];
        __syncthreads();
        int j = tid & 127;
        const float* W = (tid < 128) ? (Wa + 256 * DIN) : (Wg + 128 * DIN);
        float acc = 0.f;
#pragma unroll 8
        for (int k = 0; k < DIN; k++) acc += s[k] * W[k * DIN + j];
        float* o = (tid < 128) ? Ta : Tg;
        o[row * DIN + j] = acc;
    } else {
        int i = (b - PACK_BLOCKS - SMALL_BLOCKS) * 256 + tid;
        if (i < NUM_TRI) atomicAdd(&freq[trip[i * 3 + 2]], 1);
    }
}

// ---------------- K2: MFMA entity GEMMs: {Pt,Ph,Gh} = X @ {Wa_t,Wa_h,Wg_h} (+bias) ----
__global__ __launch_bounds__(256) void k_entmm(const float* __restrict__ X,
                                               const unsigned short* __restrict__ Bpack,
                                               const float* __restrict__ ba,
                                               const float* __restrict__ bg,
                                               float* __restrict__ Pt,
                                               float* __restrict__ Ph,
                                               float* __restrict__ Gh) {
    __shared__ unsigned short As[64][136];   // +8 cols pad: 2-way bank alias (free)
    int tid = threadIdx.x;
    int m0 = blockIdx.x * 64;

    // stage X tile as bf16
    for (int i = 0; i < 8; i++) {
        int v = tid + i * 256;                // float4 index in 64x128 tile
        int row = v >> 5;
        int c4 = v & 31;
        int gr = m0 + row;
        if (gr >= NUM_ENT) gr = NUM_ENT - 1;
        float4 x = *(const float4*)&X[gr * DIN + c4 * 4];
        ushort4 h;
        h.x = f2bf(x.x); h.y = f2bf(x.y); h.z = f2bf(x.z); h.w = f2bf(x.w);
        *(ushort4*)&As[row][c4 * 4] = h;
    }
    __syncthreads();

    int w = tid >> 6;            // wave id: rows w*16..w*16+15
    int q = tid & 63;            // lane
    int mrow = (q & 15) + w * 16;
    int quad = q >> 4;

    f32x4 acc[3][8];
#pragma unroll
    for (int s = 0; s < 3; s++)
#pragma unroll
        for (int t = 0; t < 8; t++) acc[s][t] = (f32x4){0.f, 0.f, 0.f, 0.f};

    const bf16x8* Bp = (const bf16x8*)Bpack;
#pragma unroll
    for (int ks = 0; ks < 4; ks++) {
        bf16x8 a = *(const bf16x8*)&As[mrow][ks * 32 + quad * 8];
#pragma unroll
        for (int s = 0; s < 3; s++) {
#pragma unroll
            for (int t = 0; t < 8; t++) {
                bf16x8 bfr = Bp[((s * 8 + t) * 4 + ks) * 64 + q];
                acc[s][t] = __builtin_amdgcn_mfma_f32_16x16x32_bf16(a, bfr, acc[s][t], 0, 0, 0);
            }
        }
    }

    // epilogue: C/D layout col=lane&15, row=(lane>>4)*4+reg
    int col = q & 15;
    int r0 = quad * 4;
#pragma unroll
    for (int t = 0; t < 8; t++) {
        int n = t * 16 + col;
        float bva = ba[n];
        float bvg = bg[n];
#pragma unroll
        for (int rr = 0; rr < 4; rr++) {
            int gr = m0 + w * 16 + r0 + rr;
            if (gr < NUM_ENT) {
                Pt[gr * DIN + n] = acc[0][t][rr] + bva;
                Ph[gr * DIN + n] = acc[1][t][rr];
                Gh[gr * DIN + n] = acc[2][t][rr] + bvg;
            }
        }
    }
}

// ---------------- scan 1: per-chunk inclusive scan + chunk totals ----------------
__global__ __launch_bounds__(SCAN_BLK) void k_scan1(const int* __restrict__ freq,
                                                    int* __restrict__ incl,
                                                    int* __restrict__ btot) {
    int gid = blockIdx.x * SCAN_BLK + threadIdx.x;
    int lane = threadIdx.x & 63;
    int wv = threadIdx.x >> 6;
    int s = (gid < NUM_ENT) ? freq[gid] : 0;
#pragma unroll
    for (int off = 1; off < 64; off <<= 1) {
        int n = __shfl_up(s, off, 64);
        if (lane >= off) s += n;
    }
    __shared__ int wtot[16];
    if (lane == 63) wtot[wv] = s;
    __syncthreads();
    if (wv == 0 && lane < 16) {
        int w = wtot[lane];
#pragma unroll
        for (int off = 1; off < 16; off <<= 1) {
            int n = __shfl_up(w, off, 64);
            if (lane >= off) w += n;
        }
        wtot[lane] = w;
    }
    __syncthreads();
    if (wv > 0) s += wtot[wv - 1];
    if (gid < NUM_ENT) incl[gid] = s;
    if (threadIdx.x == SCAN_BLK - 1) btot[blockIdx.x] = s;
}

// ---------------- scan 2: inclusive scan of chunk totals ----------------
__global__ void k_scan2(int* __restrict__ btot) {
    int lane = threadIdx.x;
    int v = (lane < NB) ? btot[lane] : 0;
#pragma unroll
    for (int off = 1; off < 64; off <<= 1) {
        int n = __shfl_up(v, off, 64);
        if (lane >= off) v += n;
    }
    if (lane < NB) btot[lane] = v;
}

// ---------------- scan 3: exclusive offsets ----------------
__global__ __launch_bounds__(SCAN_BLK) void k_scan3(int* __restrict__ incl_to_excl,
                                                    const int* __restrict__ freq,
                                                    const int* __restrict__ btot) {
    int gid = blockIdx.x * SCAN_BLK + threadIdx.x;
    if (gid < NUM_ENT) {
        int base = (blockIdx.x > 0) ? btot[blockIdx.x - 1] : 0;
        incl_to_excl[gid] = incl_to_excl[gid] + base - freq[gid];
    }
}

// ---------------- scatter tail-sorted (h,r) edge list ----------------
__global__ void k_scatter(const int* __restrict__ trip, const int* __restrict__ excl,
                          int* __restrict__ cursor, int2* __restrict__ elist2) {
    int i = blockIdx.x * blockDim.x + threadIdx.x;
    if (i < NUM_TRI) {
        int h = trip[i * 3 + 0];
        int r = trip[i * 3 + 1];
        int t = trip[i * 3 + 2];
        int pos = excl[t] + atomicAdd(&cursor[t], 1);
        elist2[pos] = make_int2(h, r);
    }
}

// ---------------- fused per-tail online-softmax pass (float4, 32 lanes/tail) --------
__global__ __launch_bounds__(128) void k_fused(const int2* __restrict__ elist2,
                                               const int* __restrict__ excl,
                                               const int* __restrict__ freq,
                                               const float* __restrict__ Pt,
                                               const float* __restrict__ Ph,
                                               const float* __restrict__ Gh,
                                               const float* __restrict__ Ta,
                                               const float* __restrict__ Tg,
                                               const float* __restrict__ attn_vec,
                                               float* __restrict__ out) {
    int tid = threadIdx.x;
    int g = tid >> 5;
    int q = tid & 31;
    int t = blockIdx.x * 4 + g;
    int off = excl[t];
    int deg = freq[t];
    int c = q * 4;

    float4 pt4 = *(const float4*)&Pt[t * DIN + c];
    float4 av4 = *(const float4*)&attn_vec[c];

    float m = -INFINITY, l = 0.f;
    float4 acc = make_float4(0.f, 0.f, 0.f, 0.f);
    float4 sTa = make_float4(0.f, 0.f, 0.f, 0.f);
    float4 sTg = make_float4(0.f, 0.f, 0.f, 0.f);

    for (int it = 0; it <= deg; it++) {
        float4 pa, gm;
        if (it < deg) {
            int2 hr = elist2[off + it];
            float4 ta = *(const float4*)&Ta[hr.y * DIN + c];
            float4 tg = *(const float4*)&Tg[hr.y * DIN + c];
            sTa = f4add(sTa, ta);
            sTg = f4add(sTg, tg);
            pa = f4add(*(const float4*)&Ph[hr.x * DIN + c], ta);
            gm = f4add(*(const float4*)&Gh[hr.x * DIN + c], tg);
        } else {
            float inv = (deg > 0) ? __builtin_amdgcn_rcpf((float)deg) : 0.f;
            pa = *(const float4*)&Ph[t * DIN + c];
            gm = *(const float4*)&Gh[t * DIN + c];
            pa.x += sTa.x * inv; pa.y += sTa.y * inv; pa.z += sTa.z * inv; pa.w += sTa.w * inv;
            gm.x += sTg.x * inv; gm.y += sTg.y * inv; gm.z += sTg.z * inv; gm.w += sTg.w * inv;
        }
        float p = tanh_dot4(f4add(pt4, pa), av4);
        p += __shfl_xor(p, 1);
        p += __shfl_xor(p, 2);
        float nm = fmaxf(m, p);
        float al = __expf(m - nm);
        float w  = __expf(p - nm);
        l = l * al + w;
        acc.x = acc.x * al + w * gm.x;
        acc.y = acc.y * al + w * gm.y;
        acc.z = acc.z * al + w * gm.z;
        acc.w = acc.w * al + w * gm.w;
        m = nm;
    }
    float invl = 1.f / (l + 1e-16f);
    *(float4*)&out[t * DIN + c] =
        make_float4(acc.x * invl, acc.y * invl, acc.z * invl, acc.w * invl);
}

extern "C" void kernel_launch(void* const* d_in, const int* in_sizes, int n_in,
                              void* d_out, int out_size, void* d_ws, size_t ws_size,
                              hipStream_t stream) {
    const float* emb_ent  = (const float*)d_in[0];
    const float* emb_rel  = (const float*)d_in[1];
    const int*   trip     = (const int*)d_in[2];
    const float* Wa       = (const float*)d_in[3];
    const float* ba       = (const float*)d_in[4];
    const float* attn_vec = (const float*)d_in[5];
    const float* Wg       = (const float*)d_in[6];
    const float* bg       = (const float*)d_in[7];
    float* out = (float*)d_out;

    // workspace layout (float-element offsets)
    float* wsf = (float*)d_ws;
    float*          Pt     = wsf;                           //  6,400,000
    float*          Ph     = wsf + 6400000;                 //  6,400,000
    float*          Gh     = wsf + 12800000;                //  6,400,000
    float*          Ta     = wsf + 19200000;                //      8,192
    float*          Tg     = wsf + 19208192;                //      8,192
    unsigned short* Bpack  = (unsigned short*)(wsf + 19216384); // 49,152 us = 24,576 f
    int*            freq   = (int*)(wsf + 19240960);        //     50,000 (zeroed)
    int*            cursor = freq + 50000;                  //     50,000 (zeroed)
    int*            btot   = cursor + 50000;                //         64
    int*            excl   = btot + 64;                     //     50,000
    int2*           elist2 = (int2*)(excl + 50000);         //    400,000 int2
    // total ≈ 20,191,024 floats ≈ 80.8 MB

    hipMemsetAsync(freq, 0, (size_t)100000 * 4, stream);

    k_prep<<<PREP_BLOCKS, 256, 0, stream>>>(emb_rel, trip, Wa, Wg, Bpack, Ta, Tg, freq);

    k_entmm<<<(NUM_ENT + 63) / 64, 256, 0, stream>>>(emb_ent, Bpack, ba, bg, Pt, Ph, Gh);

    k_scan1<<<NB, SCAN_BLK, 0, stream>>>(freq, excl, btot);
    k_scan2<<<1, 64, 0, stream>>>(btot);
    k_scan3<<<NB, SCAN_BLK, 0, stream>>>(excl, freq, btot);

    k_scatter<<<(NUM_TRI + 255) / 256, 256, 0, stream>>>(trip, excl, cursor, elist2);

    k_fused<<<NUM_ENT / 4, 128, 0, stream>>>(elist2, excl, freq,
                                             Pt, Ph, Gh, Ta, Tg, attn_vec, out);
}